// Round 5
// baseline (46.909 us; speedup 1.0000x reference)
//
#include <hip/hip_runtime.h>
#include <hip/hip_bf16.h>

typedef __attribute__((ext_vector_type(8))) short bf16x8;
typedef __attribute__((ext_vector_type(4))) float f32x4;
typedef __attribute__((ext_vector_type(4))) unsigned int u32x4;

#define DD 1024
#define KC 256
#define BM 64
#define BK 64
#define KSTEPS (DD / BK)      // 16
#define ABYTES 8192           // A region per buffer (64x64 bf16)
#define BUF_BYTES 40960       // A (8KB) + B (32KB) per buffer
#define CLAMP_EPS 1e-8f

__device__ __forceinline__ unsigned int pk2(float x, float y) {
  __hip_bfloat162 h = __float22bfloat162_rn(float2{x, y});
  return *reinterpret_cast<unsigned int*>(&h);
}

__device__ __forceinline__ bf16x8 cvt8(f32x4 lo, f32x4 hi) {
  u32x4 w;
  w[0] = pk2(lo[0], lo[1]);
  w[1] = pk2(lo[2], lo[3]);
  w[2] = pk2(hi[0], hi[1]);
  w[3] = pk2(hi[2], hi[3]);
  return __builtin_bit_cast(bf16x8, w);
}

// Single fused kernel: cosine-sim GEMM with BOTH norms computed in-kernel.
// A (64 rows of x, fp32->bf16) and B (all 256 raw centers, fp32->bf16,
// L2-resident re-read) staged through regs into double-buffered swizzled LDS.
// ssq for x-rows and c-rows accumulated during staging; epilogue applies
// 0.5 * dot * invx * invc + 0.5.
__global__ __launch_bounds__(512, 4) void cossim_fused_kernel(
    const float* __restrict__ x, const float* __restrict__ c,
    float* __restrict__ out) {
  __shared__ __align__(16) char lds_raw[2 * BUF_BYTES];   // 80 KB

  const int t = threadIdx.x;
  const int lane = t & 63;
  const int wid = t >> 6;
  const int wm = wid >> 2;     // 0..1
  const int wn = wid & 3;      // 0..3
  const int fr = lane & 15;
  const int row0 = blockIdx.x * BM;

  // staging geometry (A and B share it): thread owns row rb, 8-elem segment seg
  const int rb = t >> 3;       // 0..63
  const int seg = t & 7;       // 0..7
  const float* aptr = x + (size_t)(row0 + rb) * DD + seg * 8;
  const float* bptr = c + (size_t)rb * DD + seg * 8;
  const int sAB = (rb * BK + seg * 8) ^ ((rb & 7) << 3);   // swizzled, shorts

  float ssqx = 0.f;
  float ssqb0 = 0.f, ssqb1 = 0.f, ssqb2 = 0.f, ssqb3 = 0.f;
  f32x4 rA0, rA1;

  // stage B tile `ks` (4 row-passes: rb, rb+64, rb+128, rb+192) into buffer
#define STAGE_B(buf, ks) do {                                               \
    short* bs = (short*)(lds_raw + (buf) * BUF_BYTES + ABYTES);             \
    const float* g0 = bptr + (ks) * BK;                                     \
    f32x4 u0 = *(const f32x4*)(g0);                                         \
    f32x4 u1 = *(const f32x4*)(g0 + 4);                                     \
    f32x4 v0 = *(const f32x4*)(g0 + 64 * DD);                               \
    f32x4 v1 = *(const f32x4*)(g0 + 64 * DD + 4);                           \
    f32x4 w0 = *(const f32x4*)(g0 + 128 * DD);                              \
    f32x4 w1 = *(const f32x4*)(g0 + 128 * DD + 4);                          \
    f32x4 z0 = *(const f32x4*)(g0 + 192 * DD);                              \
    f32x4 z1 = *(const f32x4*)(g0 + 192 * DD + 4);                          \
    _Pragma("unroll")                                                       \
    for (int j = 0; j < 4; ++j) {                                           \
      ssqb0 = fmaf(u0[j], u0[j], ssqb0); ssqb0 = fmaf(u1[j], u1[j], ssqb0); \
      ssqb1 = fmaf(v0[j], v0[j], ssqb1); ssqb1 = fmaf(v1[j], v1[j], ssqb1); \
      ssqb2 = fmaf(w0[j], w0[j], ssqb2); ssqb2 = fmaf(w1[j], w1[j], ssqb2); \
      ssqb3 = fmaf(z0[j], z0[j], ssqb3); ssqb3 = fmaf(z1[j], z1[j], ssqb3); \
    }                                                                       \
    *(bf16x8*)&bs[sAB]            = cvt8(u0, u1);                           \
    *(bf16x8*)&bs[sAB + 64 * BK]  = cvt8(v0, v1);                           \
    *(bf16x8*)&bs[sAB + 128 * BK] = cvt8(w0, w1);                           \
    *(bf16x8*)&bs[sAB + 192 * BK] = cvt8(z0, z1);                           \
  } while (0)

  // stage A tile from rA0/rA1 into buffer
#define STAGE_A(buf) do {                                                   \
    _Pragma("unroll")                                                       \
    for (int j = 0; j < 4; ++j) {                                           \
      ssqx = fmaf(rA0[j], rA0[j], ssqx);                                    \
      ssqx = fmaf(rA1[j], rA1[j], ssqx);                                    \
    }                                                                       \
    short* as = (short*)(lds_raw + (buf) * BUF_BYTES);                      \
    *(bf16x8*)&as[sAB] = cvt8(rA0, rA1);                                    \
  } while (0)

  // ---- prologue: stage tile 0, prefetch A tile 1
  rA0 = *(const f32x4*)(aptr);
  rA1 = *(const f32x4*)(aptr + 4);
  STAGE_B(0, 0);
  STAGE_A(0);
  rA0 = *(const f32x4*)(aptr + BK);
  rA1 = *(const f32x4*)(aptr + BK + 4);
  __syncthreads();

  f32x4 acc[2][4];
  #pragma unroll
  for (int i = 0; i < 2; ++i)
    #pragma unroll
    for (int j = 0; j < 4; ++j) acc[i][j] = (f32x4)(0.f);

  #pragma unroll
  for (int ks = 0; ks < KSTEPS; ++ks) {
    const int cb = ks & 1;
    const int nb = cb ^ 1;
    // ---- stage tile ks+1 into buffer nb
    if (ks + 1 < KSTEPS) {
      STAGE_B(nb, ks + 1);
      STAGE_A(nb);
    }
    // ---- prefetch A tile ks+2 into regs (spans this window's barrier)
    f32x4 pA0, pA1;
    if (ks + 2 < KSTEPS) {
      pA0 = *(const f32x4*)(aptr + (ks + 2) * BK);
      pA1 = *(const f32x4*)(aptr + (ks + 2) * BK + 4);
    }
    // ---- compute tile ks from buffer cb
    {
      const short* asb = (const short*)(lds_raw + cb * BUF_BYTES);
      const short* bsb = (const short*)(lds_raw + cb * BUF_BYTES + ABYTES);
      const int swz = (fr & 7) << 3;
      #pragma unroll
      for (int ksub = 0; ksub < 2; ++ksub) {
        const int kk = ksub * 32 + (lane >> 4) * 8;
        bf16x8 af0 = *(const bf16x8*)&asb[((wm * 32 + fr) * BK + kk) ^ swz];
        bf16x8 af1 = *(const bf16x8*)&asb[((wm * 32 + 16 + fr) * BK + kk) ^ swz];
        bf16x8 bf0 = *(const bf16x8*)&bsb[((wn * 64 + fr) * BK + kk) ^ swz];
        bf16x8 bf1 = *(const bf16x8*)&bsb[((wn * 64 + 16 + fr) * BK + kk) ^ swz];
        bf16x8 bf2 = *(const bf16x8*)&bsb[((wn * 64 + 32 + fr) * BK + kk) ^ swz];
        bf16x8 bf3 = *(const bf16x8*)&bsb[((wn * 64 + 48 + fr) * BK + kk) ^ swz];
        acc[0][0] = __builtin_amdgcn_mfma_f32_16x16x32_bf16(af0, bf0, acc[0][0], 0, 0, 0);
        acc[0][1] = __builtin_amdgcn_mfma_f32_16x16x32_bf16(af0, bf1, acc[0][1], 0, 0, 0);
        acc[0][2] = __builtin_amdgcn_mfma_f32_16x16x32_bf16(af0, bf2, acc[0][2], 0, 0, 0);
        acc[0][3] = __builtin_amdgcn_mfma_f32_16x16x32_bf16(af0, bf3, acc[0][3], 0, 0, 0);
        acc[1][0] = __builtin_amdgcn_mfma_f32_16x16x32_bf16(af1, bf0, acc[1][0], 0, 0, 0);
        acc[1][1] = __builtin_amdgcn_mfma_f32_16x16x32_bf16(af1, bf1, acc[1][1], 0, 0, 0);
        acc[1][2] = __builtin_amdgcn_mfma_f32_16x16x32_bf16(af1, bf2, acc[1][2], 0, 0, 0);
        acc[1][3] = __builtin_amdgcn_mfma_f32_16x16x32_bf16(af1, bf3, acc[1][3], 0, 0, 0);
      }
    }
    if (ks + 1 < KSTEPS) __syncthreads();
    if (ks + 2 < KSTEPS) { rA0 = pA0; rA1 = pA1; }
  }
#undef STAGE_A
#undef STAGE_B

  // ---- reduce ssq over the 8 segment-owner lanes (t&7 groups)
  ssqx  += __shfl_xor(ssqx, 1, 64);  ssqx  += __shfl_xor(ssqx, 2, 64);  ssqx  += __shfl_xor(ssqx, 4, 64);
  ssqb0 += __shfl_xor(ssqb0, 1, 64); ssqb0 += __shfl_xor(ssqb0, 2, 64); ssqb0 += __shfl_xor(ssqb0, 4, 64);
  ssqb1 += __shfl_xor(ssqb1, 1, 64); ssqb1 += __shfl_xor(ssqb1, 2, 64); ssqb1 += __shfl_xor(ssqb1, 4, 64);
  ssqb2 += __shfl_xor(ssqb2, 1, 64); ssqb2 += __shfl_xor(ssqb2, 2, 64); ssqb2 += __shfl_xor(ssqb2, 4, 64);
  ssqb3 += __shfl_xor(ssqb3, 1, 64); ssqb3 += __shfl_xor(ssqb3, 2, 64); ssqb3 += __shfl_xor(ssqb3, 4, 64);

  // buffer 0's A-region is dead (last read: window 14, barrier'd); reuse it.
  float* invx_l = (float*)lds_raw;            // 64 floats
  float* invc_l = (float*)(lds_raw + 256);    // 256 floats
  if (seg == 0) {
    invx_l[rb]       = 1.f / fmaxf(sqrtf(ssqx),  CLAMP_EPS);
    invc_l[rb]       = 1.f / fmaxf(sqrtf(ssqb0), CLAMP_EPS);
    invc_l[rb + 64]  = 1.f / fmaxf(sqrtf(ssqb1), CLAMP_EPS);
    invc_l[rb + 128] = 1.f / fmaxf(sqrtf(ssqb2), CLAMP_EPS);
    invc_l[rb + 192] = 1.f / fmaxf(sqrtf(ssqb3), CLAMP_EPS);
  }
  __syncthreads();

  // ---- epilogue: C/D layout col=lane&15, row=(lane>>4)*4+reg
  float vch[4];
  #pragma unroll
  for (int fn = 0; fn < 4; ++fn)
    vch[fn] = invc_l[wn * 64 + fn * 16 + fr] * 0.5f;
  #pragma unroll
  for (int fm = 0; fm < 2; ++fm) {
    #pragma unroll
    for (int r = 0; r < 4; ++r) {
      const int rl = wm * 32 + fm * 16 + (lane >> 4) * 4 + r;
      const float iv = invx_l[rl];
      float* orow = out + (size_t)(row0 + rl) * KC + wn * 64 + fr;
      #pragma unroll
      for (int fn = 0; fn < 4; ++fn)
        orow[fn * 16] = fmaf(acc[fm][fn][r] * iv, vch[fn], 0.5f);
    }
  }
}

extern "C" void kernel_launch(void* const* d_in, const int* in_sizes, int n_in,
                              void* d_out, int out_size, void* d_ws, size_t ws_size,
                              hipStream_t stream) {
  const float* x = (const float*)d_in[0];
  const float* c = (const float*)d_in[1];
  float* out = (float*)d_out;
  const int nrows = in_sizes[0] / DD;    // 32768
  cossim_fused_kernel<<<nrows / BM, 512, 0, stream>>>(x, c, out);
}

// Round 6
// 39.647 us; speedup vs baseline: 1.1832x; 1.1832x over previous
//
#include <hip/hip_runtime.h>
#include <hip/hip_bf16.h>

typedef __attribute__((ext_vector_type(8))) short bf16x8;
typedef __attribute__((ext_vector_type(4))) float f32x4;
typedef __attribute__((ext_vector_type(4))) unsigned int u32x4;

#define DD 1024
#define KC 256
#define BM 64
#define BK 64
#define KSTEPS (DD / BK)      // 16
#define BUF_BYTES 40960       // As (8KB) + Bs (32KB) per buffer
#define CLAMP_EPS 1e-8f

__device__ __forceinline__ unsigned short f2bf(float f) {
  unsigned int u = __float_as_uint(f);
  u += 0x7FFFu + ((u >> 16) & 1u);   // RNE
  return (unsigned short)(u >> 16);
}

__device__ __forceinline__ unsigned int pk2(float x, float y) {
  __hip_bfloat162 h = __float22bfloat162_rn(float2{x, y});
  return *reinterpret_cast<unsigned int*>(&h);
}

__device__ __forceinline__ bf16x8 cvt8(f32x4 lo, f32x4 hi) {
  u32x4 w;
  w[0] = pk2(lo[0], lo[1]);
  w[1] = pk2(lo[2], lo[3]);
  w[2] = pk2(hi[0], hi[1]);
  w[3] = pk2(hi[2], hi[3]);
  return __builtin_bit_cast(bf16x8, w);
}

// async global->LDS, 16B per lane; LDS dest is wave-uniform base + lane*16
__device__ __forceinline__ void gload_lds16(const short* g, short* l) {
  __builtin_amdgcn_global_load_lds(
      (__attribute__((address_space(1))) void*)g,
      (__attribute__((address_space(3))) void*)l, 16, 0, 0);
}

// Kernel 1: per-center inverse-norm + prenormalized bf16 copy into ws.
__global__ __launch_bounds__(64) void center_norm_kernel(
    const float* __restrict__ c, short* __restrict__ cn) {
  const int k = blockIdx.x;
  const int lane = threadIdx.x;
  const float* row = c + (size_t)k * DD + lane * 16;
  f32x4 v0 = *(const f32x4*)(row);
  f32x4 v1 = *(const f32x4*)(row + 4);
  f32x4 v2 = *(const f32x4*)(row + 8);
  f32x4 v3 = *(const f32x4*)(row + 12);
  float ss = 0.f;
  #pragma unroll
  for (int j = 0; j < 4; ++j)
    ss += v0[j]*v0[j] + v1[j]*v1[j] + v2[j]*v2[j] + v3[j]*v3[j];
  #pragma unroll
  for (int off = 32; off > 0; off >>= 1) ss += __shfl_xor(ss, off, 64);
  const float inv = 1.f / fmaxf(sqrtf(ss), CLAMP_EPS);
  bf16x8 lo, hi;
  #pragma unroll
  for (int j = 0; j < 4; ++j) {
    lo[j]     = (short)f2bf(v0[j] * inv);
    lo[j + 4] = (short)f2bf(v1[j] * inv);
    hi[j]     = (short)f2bf(v2[j] * inv);
    hi[j + 4] = (short)f2bf(v3[j] * inv);
  }
  short* o = cn + (size_t)k * DD + lane * 16;
  *(bf16x8*)o = lo;
  *(bf16x8*)(o + 8) = hi;
}

// Kernel 2: fused cosine-sim GEMM, double-buffered LDS, 1 barrier per K-step.
// R6 deltas vs R3: A-prefetch issued FIRST in the loop body; NT out stores;
// one fewer epilogue barrier. Sync is plain __syncthreads (proven).
__global__ __launch_bounds__(512, 4) void cossim_gemm_kernel(
    const float* __restrict__ x, const short* __restrict__ cn,
    float* __restrict__ out) {
  __shared__ __align__(16) char lds_raw[2 * BUF_BYTES];   // 80 KB

  const int t = threadIdx.x;
  const int lane = t & 63;
  const int wid = t >> 6;
  const int wm = wid >> 2;     // 0..1
  const int wn = wid & 3;      // 0..3
  const int fr = lane & 15;
  const int row0 = blockIdx.x * BM;

  // ---- A staging geometry: thread owns (row ar, 8-float segment aseg)
  const int ar = t >> 3;
  const int aseg = t & 7;
  const float* aptr = x + (size_t)(row0 + ar) * DD + aseg * 8;
  const int sA = (ar * BK + aseg * 8) ^ ((ar & 7) << 3);   // swizzled, shorts

  // ---- B staging via gload_lds: pre-swizzled source, linear LDS dest
  const short* bsrc0; const short* bsrc1; const short* bsrc2; const short* bsrc3;
  int bld0, bld1, bld2, bld3;
  {
    #define BGEO(i, PS, PL) {                       \
      const int g = (wid * 4 + (i)) * 64 + lane;    \
      const int n = g >> 3;                         \
      const int cp = (g & 7) ^ (n & 7);             \
      PS = cn + n * DD + cp * 8;                    \
      PL = (wid * 4 + (i)) * 512; }
    BGEO(0, bsrc0, bld0) BGEO(1, bsrc1, bld1)
    BGEO(2, bsrc2, bld2) BGEO(3, bsrc3, bld3)
    #undef BGEO
  }

  float ssq = 0.f;

  // ---- prologue: stage tile 0 into buffer 0, prefetch A tile 1
  f32x4 rA0 = *(const f32x4*)(aptr);
  f32x4 rA1 = *(const f32x4*)(aptr + 4);
  {
    short* bsb = (short*)(lds_raw + 8192);
    gload_lds16(bsrc0, bsb + bld0);
    gload_lds16(bsrc1, bsb + bld1);
    gload_lds16(bsrc2, bsb + bld2);
    gload_lds16(bsrc3, bsb + bld3);
  }
  #pragma unroll
  for (int j = 0; j < 4; ++j) {
    ssq = fmaf(rA0[j], rA0[j], ssq);
    ssq = fmaf(rA1[j], rA1[j], ssq);
  }
  *(bf16x8*)&((short*)lds_raw)[sA] = cvt8(rA0, rA1);
  rA0 = *(const f32x4*)(aptr + BK);
  rA1 = *(const f32x4*)(aptr + BK + 4);
  __syncthreads();

  f32x4 acc[2][4];
  #pragma unroll
  for (int i = 0; i < 2; ++i)
    #pragma unroll
    for (int j = 0; j < 4; ++j) acc[i][j] = (f32x4)(0.f);

  #pragma unroll
  for (int ks = 0; ks < KSTEPS; ++ks) {
    const int cb = ks & 1;
    const int nb = cb ^ 1;
    // ---- 1. issue A reg loads for tile ks+2 FIRST (earliest issue ->
    //         most latency covered before this window's barrier drain)
    f32x4 pA0, pA1;
    if (ks + 2 < KSTEPS) {
      pA0 = *(const f32x4*)(aptr + (ks + 2) * BK);
      pA1 = *(const f32x4*)(aptr + (ks + 2) * BK + 4);
    }
    // ---- 2. issue B gloads for tile ks+1
    if (ks + 1 < KSTEPS) {
      short* bsb = (short*)(lds_raw + nb * BUF_BYTES + 8192);
      gload_lds16(bsrc0 + (ks + 1) * BK, bsb + bld0);
      gload_lds16(bsrc1 + (ks + 1) * BK, bsb + bld1);
      gload_lds16(bsrc2 + (ks + 1) * BK, bsb + bld2);
      gload_lds16(bsrc3 + (ks + 1) * BK, bsb + bld3);
      // ---- 3. ssq + cvt + ds_write of tile ks+1 from regs
      #pragma unroll
      for (int j = 0; j < 4; ++j) {
        ssq = fmaf(rA0[j], rA0[j], ssq);
        ssq = fmaf(rA1[j], rA1[j], ssq);
      }
      short* asb = (short*)(lds_raw + nb * BUF_BYTES);
      *(bf16x8*)&asb[sA] = cvt8(rA0, rA1);
    }
    // ---- 4. compute tile ks from buffer cb
    {
      const short* asb = (const short*)(lds_raw + cb * BUF_BYTES);
      const short* bsb = (const short*)(lds_raw + cb * BUF_BYTES + 8192);
      const int swz = (fr & 7) << 3;
      #pragma unroll
      for (int ksub = 0; ksub < 2; ++ksub) {
        const int kk = ksub * 32 + (lane >> 4) * 8;
        bf16x8 af0 = *(const bf16x8*)&asb[((wm * 32 + fr) * BK + kk) ^ swz];
        bf16x8 af1 = *(const bf16x8*)&asb[((wm * 32 + 16 + fr) * BK + kk) ^ swz];
        bf16x8 bf0 = *(const bf16x8*)&bsb[((wn * 64 + fr) * BK + kk) ^ swz];
        bf16x8 bf1 = *(const bf16x8*)&bsb[((wn * 64 + 16 + fr) * BK + kk) ^ swz];
        bf16x8 bf2 = *(const bf16x8*)&bsb[((wn * 64 + 32 + fr) * BK + kk) ^ swz];
        bf16x8 bf3 = *(const bf16x8*)&bsb[((wn * 64 + 48 + fr) * BK + kk) ^ swz];
        acc[0][0] = __builtin_amdgcn_mfma_f32_16x16x32_bf16(af0, bf0, acc[0][0], 0, 0, 0);
        acc[0][1] = __builtin_amdgcn_mfma_f32_16x16x32_bf16(af0, bf1, acc[0][1], 0, 0, 0);
        acc[0][2] = __builtin_amdgcn_mfma_f32_16x16x32_bf16(af0, bf2, acc[0][2], 0, 0, 0);
        acc[0][3] = __builtin_amdgcn_mfma_f32_16x16x32_bf16(af0, bf3, acc[0][3], 0, 0, 0);
        acc[1][0] = __builtin_amdgcn_mfma_f32_16x16x32_bf16(af1, bf0, acc[1][0], 0, 0, 0);
        acc[1][1] = __builtin_amdgcn_mfma_f32_16x16x32_bf16(af1, bf1, acc[1][1], 0, 0, 0);
        acc[1][2] = __builtin_amdgcn_mfma_f32_16x16x32_bf16(af1, bf2, acc[1][2], 0, 0, 0);
        acc[1][3] = __builtin_amdgcn_mfma_f32_16x16x32_bf16(af1, bf3, acc[1][3], 0, 0, 0);
      }
    }
    if (ks + 1 < KSTEPS) __syncthreads();
    if (ks + 2 < KSTEPS) { rA0 = pA0; rA1 = pA1; }
  }

  // ---- per-row inverse norm: reduce over the 8 segment-owner lanes
  ssq += __shfl_xor(ssq, 1, 64);
  ssq += __shfl_xor(ssq, 2, 64);
  ssq += __shfl_xor(ssq, 4, 64);
  // buffer 0's A-region is dead (last read ks=14, barrier'd at end of ks=14)
  float* invx = (float*)lds_raw;
  if (aseg == 0) invx[ar] = 1.f / fmaxf(sqrtf(ssq), CLAMP_EPS);
  __syncthreads();

  // ---- epilogue: C/D layout col=lane&15, row=(lane>>4)*4+reg; NT stores
  #pragma unroll
  for (int fm = 0; fm < 2; ++fm) {
    #pragma unroll
    for (int r = 0; r < 4; ++r) {
      const int rl = wm * 32 + fm * 16 + (lane >> 4) * 4 + r;
      const float inv = invx[rl];
      float* orow = out + (size_t)(row0 + rl) * KC + wn * 64 + fr;
      #pragma unroll
      for (int fn = 0; fn < 4; ++fn)
        __builtin_nontemporal_store(fmaf(acc[fm][fn][r] * inv, 0.5f, 0.5f),
                                    orow + fn * 16);
    }
  }
}

extern "C" void kernel_launch(void* const* d_in, const int* in_sizes, int n_in,
                              void* d_out, int out_size, void* d_ws, size_t ws_size,
                              hipStream_t stream) {
  const float* x = (const float*)d_in[0];
  const float* c = (const float*)d_in[1];
  float* out = (float*)d_out;
  short* cn = (short*)d_ws;              // 256*1024 bf16 = 512 KB

  const int nrows = in_sizes[0] / DD;    // 32768
  center_norm_kernel<<<KC, 64, 0, stream>>>(c, cn);
  cossim_gemm_kernel<<<nrows / BM, 512, 0, stream>>>(x, cn, out);
}